// Round 6
// baseline (3830.926 us; speedup 1.0000x reference)
//
#include <hip/hip_runtime.h>
#include <hip/hip_bf16.h>

#define N_NODES 50000
#define N_EDGES 800000
#define ETOT    (N_EDGES + N_NODES)
#define DIM     256
#define NEG_SLOPE 0.2f

typedef __attribute__((ext_vector_type(4))) float  floatx4;
typedef __attribute__((ext_vector_type(4))) short  shortx4;

__device__ inline float bf2f(unsigned short u) {
    union { unsigned int i; float f; } c; c.i = ((unsigned int)u) << 16; return c.f;
}
__device__ inline unsigned short f2bf(float x) {
    union { float f; unsigned int i; } c; c.f = x;
    unsigned int r = c.i + 0x7FFF + ((c.i >> 16) & 1);
    return (unsigned short)(r >> 16);
}
__device__ inline unsigned fenc(float f) {
    unsigned u = __float_as_uint(f);
    return (u & 0x80000000u) ? ~u : (u | 0x80000000u);
}
__device__ inline float fdec(unsigned k) {
    unsigned u = (k & 0x80000000u) ? (k & 0x7FFFFFFFu) : ~k;
    return __uint_as_float(u);
}

// ---------------- dtype detection ----------------
__global__ void detect_kernel(const unsigned short* __restrict__ xs,
                              const int* __restrict__ ei, int* __restrict__ flags) {
    int tid = threadIdx.x;
    unsigned short s = xs[2 * tid];
    float av = fabsf(bf2f(s));
    int hit = (av > 0.001f && av < 100.0f) ? 1 : 0;
    int odd = ei[2 * tid + 1];
    __shared__ int sh_hit[256], sh_nz[256];
    sh_hit[tid] = hit; sh_nz[tid] = (odd != 0) ? 1 : 0;
    __syncthreads();
    for (int st = 128; st > 0; st >>= 1) {
        if (tid < st) { sh_hit[tid] += sh_hit[tid + st]; sh_nz[tid] += sh_nz[tid + st]; }
        __syncthreads();
    }
    if (tid == 0) {
        flags[0] = (sh_hit[0] < 128) ? 1 : 0;   // 1 = fp32 floats
        flags[1] = (sh_nz[0] == 0) ? 1 : 0;     // 1 = int64 edge_index
    }
}

// ---------------- input normalization ----------------
__global__ void norm_x(const void* __restrict__ src, unsigned short* __restrict__ dst,
                       const int* __restrict__ flags) {
    int i = (blockIdx.x * 256 + threadIdx.x) * 4;
    if (flags[0]) {
        const float* s = (const float*)src;
        dst[i + 0] = f2bf(s[i + 0]); dst[i + 1] = f2bf(s[i + 1]);
        dst[i + 2] = f2bf(s[i + 2]); dst[i + 3] = f2bf(s[i + 3]);
    } else {
        *(shortx4*)(dst + i) = *(const shortx4*)((const unsigned short*)src + i);
    }
}

__global__ void norm_small(const void* __restrict__ src, unsigned short* __restrict__ dst,
                           int count, const int* __restrict__ flags) {
    int i = blockIdx.x * 256 + threadIdx.x;
    if (i >= count) return;
    dst[i] = flags[0] ? f2bf(((const float*)src)[i]) : ((const unsigned short*)src)[i];
}

__global__ void norm_edges(const int* __restrict__ ei, int* __restrict__ rown,
                           int* __restrict__ coln, const int* __restrict__ flags) {
    int e = blockIdx.x * 256 + threadIdx.x;
    if (e >= N_EDGES) return;
    if (flags[1]) { rown[e] = ei[2 * e]; coln[e] = ei[2 * (N_EDGES + e)]; }
    else          { rown[e] = ei[e];     coln[e] = ei[N_EDGES + e]; }
}

// ---------------- CSR build ----------------
__global__ void zero_kernel(int* p, int n) {
    int i = blockIdx.x * 256 + threadIdx.x;
    if (i < n) p[i] = 0;
}

__global__ void init_softmax(unsigned* __restrict__ mx, float* __restrict__ den) {
    int i = blockIdx.x * 256 + threadIdx.x;
    if (i < N_NODES * 4) { mx[i] = 0u; den[i] = 0.f; }
}

__global__ void count_kernel(const int* __restrict__ coln, int* __restrict__ cnt) {
    int e = blockIdx.x * 256 + threadIdx.x;
    if (e >= ETOT) return;
    int c = (e < N_EDGES) ? coln[e] : (e - N_EDGES);
    atomicAdd(&cnt[c], 1);
}

__global__ void scan_kernel(const int* __restrict__ cnt, int* __restrict__ off) {
    __shared__ int buf[1024];
    __shared__ int carry;
    if (threadIdx.x == 0) carry = 0;
    __syncthreads();
    for (int base = 0; base < N_NODES; base += 1024) {
        int i = base + threadIdx.x;
        int v = (i < N_NODES) ? cnt[i] : 0;
        buf[threadIdx.x] = v;
        __syncthreads();
        for (int s = 1; s < 1024; s <<= 1) {
            int t = (threadIdx.x >= s) ? buf[threadIdx.x - s] : 0;
            __syncthreads();
            buf[threadIdx.x] += t;
            __syncthreads();
        }
        int incl = buf[threadIdx.x];
        int total = buf[1023];
        if (i < N_NODES) off[i] = carry + incl - v;
        __syncthreads();
        if (threadIdx.x == 0) carry += total;
        __syncthreads();
    }
    if (threadIdx.x == 0) off[N_NODES] = carry;
}

__global__ void fill_kernel(const int* __restrict__ coln, const int* __restrict__ off,
                            int* __restrict__ cursor, int* __restrict__ eidx) {
    int e = blockIdx.x * 256 + threadIdx.x;
    if (e >= ETOT) return;
    int c = (e < N_EDGES) ? coln[e] : (e - N_EDGES);
    int p = atomicAdd(&cursor[c], 1);
    eidx[off[c] + p] = e;
}

// ---------------- naive GEMM: C[m,n] = sum_k A[m,k]*W[k,n] ----------------
__global__ __launch_bounds__(256) void naive_gemm(
    const void* __restrict__ A, int a_fp32, const void* __restrict__ W, size_t wbase,
    unsigned short* __restrict__ C, const int* __restrict__ flags)
{
    __shared__ float As[256];
    int m = blockIdx.x;
    int n = threadIdx.x;
    As[n] = a_fp32 ? ((const float*)A)[(size_t)m * 256 + n]
                   : bf2f(((const unsigned short*)A)[(size_t)m * 256 + n]);
    __syncthreads();
    float acc = 0.f;
    if (flags[0]) {
        const float* Wf = (const float*)W + wbase;
#pragma unroll 8
        for (int k = 0; k < 256; k++) acc += As[k] * Wf[k * 256 + n];
    } else {
        const unsigned short* Wh = (const unsigned short*)W + wbase;
#pragma unroll 8
        for (int k = 0; k < 256; k++) acc += As[k] * bf2f(Wh[k * 256 + n]);
    }
    C[(size_t)m * 256 + n] = f2bf(acc);
}

// ---------------- scalar attention scores: one thread per (n,h) ----------------
__global__ __launch_bounds__(256) void s_scalar(
    const unsigned short* __restrict__ xw,
    const unsigned short* __restrict__ a_src,
    const unsigned short* __restrict__ a_dst,
    float* __restrict__ s_src, float* __restrict__ s_dst)
{
    int t = blockIdx.x * 256 + threadIdx.x;
    if (t >= N_NODES * 4) return;
    int n = t >> 2, h = t & 3;
    float ps = 0.f, pd = 0.f;
    for (int c = 0; c < 64; c++) {
        float xv = bf2f(xw[(size_t)n * DIM + h * 64 + c]);
        ps += xv * bf2f(a_src[h * 64 + c]);
        pd += xv * bf2f(a_dst[h * 64 + c]);
    }
    s_src[(size_t)n * 4 + h] = ps;
    s_dst[(size_t)n * 4 + h] = pd;
}

__device__ inline void edge_logit(int e, const int* rown, const int* coln,
                                  const float* ssrc, const float* sdst,
                                  int& c, float* t) {
    int r = (e < N_EDGES) ? rown[e] : (e - N_EDGES);
    c     = (e < N_EDGES) ? coln[e] : (e - N_EDGES);
    floatx4 sv = *(const floatx4*)(ssrc + (size_t)r * 4);
    floatx4 dv = *(const floatx4*)(sdst + (size_t)c * 4);
    float v0 = sv.x + dv.x, v1 = sv.y + dv.y, v2 = sv.z + dv.z, v3 = sv.w + dv.w;
    t[0] = v0 > 0.f ? v0 : NEG_SLOPE * v0;
    t[1] = v1 > 0.f ? v1 : NEG_SLOPE * v1;
    t[2] = v2 > 0.f ? v2 : NEG_SLOPE * v2;
    t[3] = v3 > 0.f ? v3 : NEG_SLOPE * v3;
}

// ---------------- segment softmax (edge-parallel atomics) ----------------
__global__ void max_kernel(const int* __restrict__ rown, const int* __restrict__ coln,
                           const float* __restrict__ ssrc, const float* __restrict__ sdst,
                           unsigned* __restrict__ mx) {
    int e = blockIdx.x * 256 + threadIdx.x;
    if (e >= ETOT) return;
    int c; float t[4];
    edge_logit(e, rown, coln, ssrc, sdst, c, t);
    atomicMax(&mx[c * 4 + 0], fenc(t[0]));
    atomicMax(&mx[c * 4 + 1], fenc(t[1]));
    atomicMax(&mx[c * 4 + 2], fenc(t[2]));
    atomicMax(&mx[c * 4 + 3], fenc(t[3]));
}

__global__ void den_kernel(const int* __restrict__ rown, const int* __restrict__ coln,
                           const float* __restrict__ ssrc, const float* __restrict__ sdst,
                           const unsigned* __restrict__ mx, float* __restrict__ den) {
    int e = blockIdx.x * 256 + threadIdx.x;
    if (e >= ETOT) return;
    int c; float t[4];
    edge_logit(e, rown, coln, ssrc, sdst, c, t);
    atomicAdd(&den[c * 4 + 0], __expf(t[0] - fdec(mx[c * 4 + 0])));
    atomicAdd(&den[c * 4 + 1], __expf(t[1] - fdec(mx[c * 4 + 1])));
    atomicAdd(&den[c * 4 + 2], __expf(t[2] - fdec(mx[c * 4 + 2])));
    atomicAdd(&den[c * 4 + 3], __expf(t[3] - fdec(mx[c * 4 + 3])));
}

__global__ void alpha_kernel(const int* __restrict__ rown, const int* __restrict__ coln,
                             const float* __restrict__ ssrc, const float* __restrict__ sdst,
                             const unsigned* __restrict__ mx, const float* __restrict__ den,
                             float* __restrict__ alpha, float* __restrict__ attn_acc,
                             float* __restrict__ attn_out, int layer) {
    int e = blockIdx.x * 256 + threadIdx.x;
    if (e >= ETOT) return;
    int c; float t[4];
    edge_logit(e, rown, coln, ssrc, sdst, c, t);
    float a0 = __expf(t[0] - fdec(mx[c * 4 + 0])) / den[c * 4 + 0];
    float a1 = __expf(t[1] - fdec(mx[c * 4 + 1])) / den[c * 4 + 1];
    float a2 = __expf(t[2] - fdec(mx[c * 4 + 2])) / den[c * 4 + 2];
    float a3 = __expf(t[3] - fdec(mx[c * 4 + 3])) / den[c * 4 + 3];
    alpha[(size_t)e * 4 + 0] = a0; alpha[(size_t)e * 4 + 1] = a1;
    alpha[(size_t)e * 4 + 2] = a2; alpha[(size_t)e * 4 + 3] = a3;
    float suma = 0.125f * (a0 + a1 + a2 + a3);
    if (layer == 0) attn_acc[e] = suma;
    else            attn_out[e] = attn_acc[e] + suma;   // fp32 output
}

// ---------------- aggregation: one wave per node ----------------
__global__ __launch_bounds__(256) void agg_gather(
    const unsigned short* __restrict__ xw, const float* __restrict__ alpha,
    const int* __restrict__ off, const int* __restrict__ eidx,
    const int* __restrict__ rown, const unsigned short* __restrict__ bias,
    unsigned short* __restrict__ h_bf, float* __restrict__ h_f32)
{
    int t = blockIdx.x * 256 + threadIdx.x;
    int n = t >> 6;
    if (n >= N_NODES) return;
    int lane = t & 63;
    int f = lane * 4;
    int h = lane >> 4;
    int base = off[n], deg = off[n + 1] - base;
    float a0 = 0.f, a1 = 0.f, a2 = 0.f, a3 = 0.f;
    for (int i = 0; i < deg; i++) {
        int e = eidx[base + i];
        int r = (e < N_EDGES) ? rown[e] : (e - N_EDGES);
        float al = alpha[(size_t)e * 4 + h];
        shortx4 xv = *(const shortx4*)(xw + (size_t)r * DIM + f);
        a0 += al * bf2f((unsigned short)xv.x);
        a1 += al * bf2f((unsigned short)xv.y);
        a2 += al * bf2f((unsigned short)xv.z);
        a3 += al * bf2f((unsigned short)xv.w);
    }
    shortx4 bv = *(const shortx4*)(bias + f);
    float o0 = a0 + bf2f((unsigned short)bv.x);
    float o1 = a1 + bf2f((unsigned short)bv.y);
    float o2 = a2 + bf2f((unsigned short)bv.z);
    float o3 = a3 + bf2f((unsigned short)bv.w);
    o0 = o0 > 0.f ? o0 : (__expf(o0) - 1.f);
    o1 = o1 > 0.f ? o1 : (__expf(o1) - 1.f);
    o2 = o2 > 0.f ? o2 : (__expf(o2) - 1.f);
    o3 = o3 > 0.f ? o3 : (__expf(o3) - 1.f);
    if (h_bf) {
        shortx4 pk;
        pk.x = (short)f2bf(o0); pk.y = (short)f2bf(o1);
        pk.z = (short)f2bf(o2); pk.w = (short)f2bf(o3);
        *(shortx4*)(h_bf + (size_t)n * DIM + f) = pk;
    }
    if (h_f32) {
        floatx4 pv; pv.x = o0; pv.y = o1; pv.z = o2; pv.w = o3;
        *(floatx4*)(h_f32 + (size_t)n * DIM + f) = pv;
    }
}

// ---------------- node predictor: wave per node, fp32 h ----------------
__global__ __launch_bounds__(256) void node_pred(
    const float* __restrict__ h, const unsigned short* __restrict__ Wn,
    const unsigned short* __restrict__ bn, float* __restrict__ outp)
{
    int wid = (blockIdx.x * 256 + threadIdx.x) >> 6;
    int lane = threadIdx.x & 63;
    if (wid >= N_NODES) return;
    int f = lane * 4;
    floatx4 hv = *(const floatx4*)(h + (size_t)wid * DIM + f);
    shortx4 wv = *(const shortx4*)(Wn + f);
    float p = hv.x * bf2f((unsigned short)wv.x) + hv.y * bf2f((unsigned short)wv.y)
            + hv.z * bf2f((unsigned short)wv.z) + hv.w * bf2f((unsigned short)wv.w);
    for (int s = 1; s < 64; s <<= 1) p += __shfl_xor(p, s);
    if (lane == 0) outp[wid] = p + bf2f(bn[0]);
}

// ---------------- edge predictor: wave per edge, fp32 h, bf16 V ----------------
__global__ __launch_bounds__(256) void edge_pred(
    const float* __restrict__ h, const unsigned short* __restrict__ V,
    const int* __restrict__ rown, const int* __restrict__ coln,
    const unsigned short* __restrict__ bb, float* __restrict__ outp, int o)
{
    int wid = (blockIdx.x * 256 + threadIdx.x) >> 6;
    int lane = threadIdx.x & 63;
    if (wid >= N_EDGES) return;
    int s = rown[wid], t = coln[wid];
    int f = lane * 4;
    floatx4 hv = *(const floatx4*)(h + (size_t)t * DIM + f);
    shortx4 vv = *(const shortx4*)(V + (size_t)s * DIM + f);
    float p = hv.x * bf2f((unsigned short)vv.x) + hv.y * bf2f((unsigned short)vv.y)
            + hv.z * bf2f((unsigned short)vv.z) + hv.w * bf2f((unsigned short)vv.w);
    for (int m = 1; m < 64; m <<= 1) p += __shfl_xor(p, m);
    if (lane == 0) outp[(size_t)wid * 3 + o] = p + bf2f(bb[o]);
}

extern "C" void kernel_launch(void* const* d_in, const int* in_sizes, int n_in,
                              void* d_out, int out_size, void* d_ws, size_t ws_size,
                              hipStream_t stream) {
    const void* x_raw  = d_in[0];
    const int*  ei_raw = (const int*)d_in[1];
    float* out = (float*)d_out;   // fp32 outputs (reference output dtype)

    char* w = (char*)d_ws;
    size_t off_b = 0;
    auto alloc = [&](size_t bytes) -> char* {
        char* p = w + off_b; off_b = (off_b + bytes + 255) & ~(size_t)255; return p;
    };
    int*            flags  = (int*)alloc(256);
    unsigned short* buf0   = (unsigned short*)alloc((size_t)N_NODES * DIM * 2); // x_bf, later Vtmp
    unsigned short* buf1   = (unsigned short*)alloc((size_t)N_NODES * DIM * 2); // xw
    unsigned short* buf2   = (unsigned short*)alloc((size_t)N_NODES * DIM * 2); // h1
    float*          alpha  = (float*)alloc((size_t)ETOT * 4 * 4);
    float*          ssrc   = (float*)alloc((size_t)N_NODES * 4 * 4);
    float*          sdst   = (float*)alloc((size_t)N_NODES * 4 * 4);
    float*          attn   = (float*)alloc((size_t)ETOT * 4);
    unsigned*       mx     = (unsigned*)alloc((size_t)N_NODES * 4 * 4);
    float*          den    = (float*)alloc((size_t)N_NODES * 4 * 4);
    int*            cnt    = (int*)alloc((size_t)2 * N_NODES * 4);
    int*            cursor = cnt + N_NODES;
    int*            offs   = (int*)alloc((size_t)(N_NODES + 1) * 4);
    int*            eidx   = (int*)alloc((size_t)ETOT * 4);
    int*            rown   = (int*)alloc((size_t)N_EDGES * 4);
    int*            coln   = (int*)alloc((size_t)N_EDGES * 4);
    unsigned short* small  = (unsigned short*)alloc(2048 * 2);
    // small: a1s@0 a1d@256 b1@512 a2s@768 a2d@1024 b2@1280 Wn@1536 bn@1792 bb@1793

    float* out_node = out;              // [50000]
    float* out_edge = out + 50000;      // [800000,3]
    float* out_h    = out + 2450000;    // [50000,256]
    float* out_attn = out + 15250000;   // [850000]

    int eb = (ETOT + 255) / 256;
    int nb4 = (N_NODES * 4 + 255) / 256;
    int node_wave_blocks = (N_NODES * 64) / 256;
    int edge_wave_blocks = (N_EDGES * 64) / 256;

    detect_kernel<<<1, 256, 0, stream>>>((const unsigned short*)x_raw, ei_raw, flags);
    norm_x<<<12500, 256, 0, stream>>>(x_raw, buf0, flags);
    norm_small<<<1, 256, 0, stream>>>(d_in[3],  small + 0,    256, flags);
    norm_small<<<1, 256, 0, stream>>>(d_in[4],  small + 256,  256, flags);
    norm_small<<<1, 256, 0, stream>>>(d_in[5],  small + 512,  256, flags);
    norm_small<<<1, 256, 0, stream>>>(d_in[7],  small + 768,  256, flags);
    norm_small<<<1, 256, 0, stream>>>(d_in[8],  small + 1024, 256, flags);
    norm_small<<<1, 256, 0, stream>>>(d_in[9],  small + 1280, 256, flags);
    norm_small<<<1, 256, 0, stream>>>(d_in[10], small + 1536, 256, flags);
    norm_small<<<1, 256, 0, stream>>>(d_in[11], small + 1792, 1,   flags);
    norm_small<<<1, 256, 0, stream>>>(d_in[13], small + 1793, 3,   flags);
    norm_edges<<<3125, 256, 0, stream>>>(ei_raw, rown, coln, flags);

    zero_kernel<<<(2 * N_NODES + 255) / 256, 256, 0, stream>>>(cnt, 2 * N_NODES);
    count_kernel<<<eb, 256, 0, stream>>>(coln, cnt);
    scan_kernel<<<1, 1024, 0, stream>>>(cnt, offs);
    fill_kernel<<<eb, 256, 0, stream>>>(coln, offs, cursor, eidx);

    // ---- layer 1: x(buf0) -> xw(buf1); h1 -> buf2 ----
    naive_gemm<<<N_NODES, 256, 0, stream>>>(buf0, 0, d_in[2], 0, buf1, flags);
    s_scalar<<<nb4, 256, 0, stream>>>(buf1, small + 0, small + 256, ssrc, sdst);
    init_softmax<<<nb4, 256, 0, stream>>>(mx, den);
    max_kernel<<<eb, 256, 0, stream>>>(rown, coln, ssrc, sdst, mx);
    den_kernel<<<eb, 256, 0, stream>>>(rown, coln, ssrc, sdst, mx, den);
    alpha_kernel<<<eb, 256, 0, stream>>>(rown, coln, ssrc, sdst, mx, den, alpha, attn, nullptr, 0);
    agg_gather<<<node_wave_blocks, 256, 0, stream>>>(buf1, alpha, offs, eidx, rown,
                                                     small + 512, buf2, nullptr);

    // ---- layer 2: h1(buf2) -> xw(buf1); final h -> out_h (fp32) ----
    naive_gemm<<<N_NODES, 256, 0, stream>>>(buf2, 0, d_in[6], 0, buf1, flags);
    s_scalar<<<nb4, 256, 0, stream>>>(buf1, small + 768, small + 1024, ssrc, sdst);
    init_softmax<<<nb4, 256, 0, stream>>>(mx, den);
    max_kernel<<<eb, 256, 0, stream>>>(rown, coln, ssrc, sdst, mx);
    den_kernel<<<eb, 256, 0, stream>>>(rown, coln, ssrc, sdst, mx, den);
    alpha_kernel<<<eb, 256, 0, stream>>>(rown, coln, ssrc, sdst, mx, den, alpha, attn, out_attn, 1);
    agg_gather<<<node_wave_blocks, 256, 0, stream>>>(buf1, alpha, offs, eidx, rown,
                                                     small + 1280, nullptr, out_h);

    // ---- heads: V_o = h @ Wb[o] -> buf0 (bf16); dots vs fp32 h ----
    for (int o = 0; o < 3; o++) {
        naive_gemm<<<N_NODES, 256, 0, stream>>>(out_h, 1, d_in[12], (size_t)o * 65536, buf0, flags);
        edge_pred<<<edge_wave_blocks, 256, 0, stream>>>(out_h, buf0, rown, coln,
                                                        small + 1793, out_edge, o);
    }
    node_pred<<<node_wave_blocks, 256, 0, stream>>>(out_h, small + 1536, small + 1792, out_node);
}

// Round 7
// 1159.792 us; speedup vs baseline: 3.3031x; 3.3031x over previous
//
#include <hip/hip_runtime.h>
#include <hip/hip_bf16.h>

#define N_NODES 50000
#define N_EDGES 800000
#define ETOT    (N_EDGES + N_NODES)
#define DIM     256
#define NEG_SLOPE 0.2f

typedef __attribute__((ext_vector_type(4))) float  floatx4;
typedef __attribute__((ext_vector_type(8))) short  shortx8;
typedef __attribute__((ext_vector_type(4))) short  shortx4;

__device__ inline float bf2f(unsigned short u) {
    union { unsigned int i; float f; } c; c.i = ((unsigned int)u) << 16; return c.f;
}
__device__ inline unsigned short f2bf(float x) {
    union { float f; unsigned int i; } c; c.f = x;
    unsigned int r = c.i + 0x7FFF + ((c.i >> 16) & 1);
    return (unsigned short)(r >> 16);
}

// ---------------- dtype detection ----------------
__global__ void detect_kernel(const unsigned short* __restrict__ xs,
                              const int* __restrict__ ei, int* __restrict__ flags) {
    int tid = threadIdx.x;
    unsigned short s = xs[2 * tid];
    float av = fabsf(bf2f(s));
    int hit = (av > 0.001f && av < 100.0f) ? 1 : 0;
    int odd = ei[2 * tid + 1];
    __shared__ int sh_hit[256], sh_nz[256];
    sh_hit[tid] = hit; sh_nz[tid] = (odd != 0) ? 1 : 0;
    __syncthreads();
    for (int st = 128; st > 0; st >>= 1) {
        if (tid < st) { sh_hit[tid] += sh_hit[tid + st]; sh_nz[tid] += sh_nz[tid + st]; }
        __syncthreads();
    }
    if (tid == 0) {
        flags[0] = (sh_hit[0] < 128) ? 1 : 0;   // 1 = fp32 floats
        flags[1] = (sh_nz[0] == 0) ? 1 : 0;     // 1 = int64 edge_index
    }
}

// ---------------- input normalization ----------------
__global__ void norm_x(const void* __restrict__ src, unsigned short* __restrict__ dst,
                       const int* __restrict__ flags) {
    int i = (blockIdx.x * 256 + threadIdx.x) * 4;
    if (flags[0]) {
        const float* s = (const float*)src;
        dst[i + 0] = f2bf(s[i + 0]); dst[i + 1] = f2bf(s[i + 1]);
        dst[i + 2] = f2bf(s[i + 2]); dst[i + 3] = f2bf(s[i + 3]);
    } else {
        *(shortx4*)(dst + i) = *(const shortx4*)((const unsigned short*)src + i);
    }
}

__global__ void norm_small(const void* __restrict__ src, unsigned short* __restrict__ dst,
                           int count, const int* __restrict__ flags) {
    int i = blockIdx.x * 256 + threadIdx.x;
    if (i >= count) return;
    dst[i] = flags[0] ? f2bf(((const float*)src)[i]) : ((const unsigned short*)src)[i];
}

__global__ void norm_edges(const int* __restrict__ ei, int* __restrict__ rown,
                           int* __restrict__ coln, const int* __restrict__ flags) {
    int e = blockIdx.x * 256 + threadIdx.x;
    if (e >= N_EDGES) return;
    if (flags[1]) { rown[e] = ei[2 * e]; coln[e] = ei[2 * (N_EDGES + e)]; }
    else          { rown[e] = ei[e];     coln[e] = ei[N_EDGES + e]; }
}

// ---------------- weight transpose (5 x [256,256] -> B^T bf16) ----------------
__global__ void transpose_kernel(const void* __restrict__ W1, const void* __restrict__ W2,
                                 const void* __restrict__ Wb, unsigned short* __restrict__ BT,
                                 const int* __restrict__ flags) {
    int idx = blockIdx.x * 256 + threadIdx.x;   // < 5*65536
    int m = idx >> 16, rem = idx & 65535;
    int k = rem >> 8, nn = rem & 255;
    const void* src = (m == 0) ? W1 : ((m == 1) ? W2 : Wb);
    size_t el = (m >= 2) ? ((size_t)(m - 2) * 65536 + rem) : (size_t)rem;
    unsigned short val = flags[0] ? f2bf(((const float*)src)[el])
                                  : ((const unsigned short*)src)[el];
    BT[(size_t)m * 65536 + nn * 256 + k] = val;
}

// ---------------- CSR build ----------------
__global__ void zero_kernel(int* p, int n) {
    int i = blockIdx.x * 256 + threadIdx.x;
    if (i < n) p[i] = 0;
}

__global__ void count_kernel(const int* __restrict__ coln, int* __restrict__ cnt) {
    int e = blockIdx.x * 256 + threadIdx.x;
    if (e >= ETOT) return;
    int c = (e < N_EDGES) ? coln[e] : (e - N_EDGES);
    atomicAdd(&cnt[c], 1);
}

__global__ void scan_kernel(const int* __restrict__ cnt, int* __restrict__ off) {
    __shared__ int buf[1024];
    __shared__ int carry;
    if (threadIdx.x == 0) carry = 0;
    __syncthreads();
    for (int base = 0; base < N_NODES; base += 1024) {
        int i = base + threadIdx.x;
        int v = (i < N_NODES) ? cnt[i] : 0;
        buf[threadIdx.x] = v;
        __syncthreads();
        for (int s = 1; s < 1024; s <<= 1) {
            int t = (threadIdx.x >= s) ? buf[threadIdx.x - s] : 0;
            __syncthreads();
            buf[threadIdx.x] += t;
            __syncthreads();
        }
        int incl = buf[threadIdx.x];
        int total = buf[1023];
        if (i < N_NODES) off[i] = carry + incl - v;
        __syncthreads();
        if (threadIdx.x == 0) carry += total;
        __syncthreads();
    }
    if (threadIdx.x == 0) off[N_NODES] = carry;
}

__global__ void fill_kernel(const int* __restrict__ coln, const int* __restrict__ off,
                            int* __restrict__ cursor, int* __restrict__ eidx) {
    int e = blockIdx.x * 256 + threadIdx.x;
    if (e >= ETOT) return;
    int c = (e < N_EDGES) ? coln[e] : (e - N_EDGES);
    int p = atomicAdd(&cursor[c], 1);
    eidx[off[c] + p] = e;
}

// ---------------- bf16 MFMA GEMM: C[M,256] = A[M,256] * B (BT given) ----------------
__global__ __launch_bounds__(256) void gemm256(
    const unsigned short* __restrict__ A,
    const unsigned short* __restrict__ BT,
    unsigned short* __restrict__ Cb, int M)
{
    __shared__ short As[128 * 32];
    __shared__ short Bs[128 * 32];
    int tid = threadIdx.x, lane = tid & 63, wave = tid >> 6;
    int wm = wave & 1, wn = wave >> 1;
    int m0 = blockIdx.x * 128, n0 = blockIdx.y * 128;
    floatx4 acc[4][4] = {};
    for (int k0 = 0; k0 < 256; k0 += 32) {
        __syncthreads();
#pragma unroll
        for (int i = 0; i < 2; i++) {
            int c = i * 256 + tid;
            int row = c >> 2, koff = (c & 3) * 8;
            int gr = m0 + row; if (gr > M - 1) gr = M - 1;
            shortx8 av = *(const shortx8*)(A + (size_t)gr * 256 + k0 + koff);
            *(shortx8*)(As + row * 32 + koff) = av;
            int gn = n0 + row;
            shortx8 bv = *(const shortx8*)(BT + (size_t)gn * 256 + k0 + koff);
            *(shortx8*)(Bs + row * 32 + koff) = bv;
        }
        __syncthreads();
        shortx8 af[4], bfr[4];
#pragma unroll
        for (int mt = 0; mt < 4; mt++)
            af[mt] = *(const shortx8*)(As + (wm * 64 + mt * 16 + (lane & 15)) * 32 + (lane >> 4) * 8);
#pragma unroll
        for (int nt = 0; nt < 4; nt++)
            bfr[nt] = *(const shortx8*)(Bs + (wn * 64 + nt * 16 + (lane & 15)) * 32 + (lane >> 4) * 8);
#pragma unroll
        for (int mt = 0; mt < 4; mt++)
#pragma unroll
            for (int nt = 0; nt < 4; nt++)
                acc[mt][nt] = __builtin_amdgcn_mfma_f32_16x16x32_bf16(af[mt], bfr[nt], acc[mt][nt], 0, 0, 0);
    }
#pragma unroll
    for (int mt = 0; mt < 4; mt++) {
#pragma unroll
        for (int r = 0; r < 4; r++) {
            int grow = m0 + wm * 64 + mt * 16 + (lane >> 4) * 4 + r;
            if (grow >= M) continue;
#pragma unroll
            for (int nt = 0; nt < 4; nt++) {
                int gcol = n0 + wn * 64 + nt * 16 + (lane & 15);
                Cb[(size_t)grow * 256 + gcol] = f2bf(acc[mt][nt][r]);
            }
        }
    }
}

// ---------------- attention scores (wave per node) ----------------
__global__ __launch_bounds__(256) void s_kernel(
    const unsigned short* __restrict__ xw,
    const unsigned short* __restrict__ a_src,
    const unsigned short* __restrict__ a_dst,
    float* __restrict__ s_src, float* __restrict__ s_dst)
{
    int wid = (blockIdx.x * 256 + threadIdx.x) >> 6;
    int lane = threadIdx.x & 63;
    if (wid >= N_NODES) return;
    int f = lane * 4;
    shortx4 xv = *(const shortx4*)(xw + (size_t)wid * DIM + f);
    shortx4 asv = *(const shortx4*)(a_src + f);
    shortx4 adv = *(const shortx4*)(a_dst + f);
    float x0 = bf2f((unsigned short)xv.x), x1 = bf2f((unsigned short)xv.y);
    float x2 = bf2f((unsigned short)xv.z), x3 = bf2f((unsigned short)xv.w);
    float ps = x0 * bf2f((unsigned short)asv.x) + x1 * bf2f((unsigned short)asv.y)
             + x2 * bf2f((unsigned short)asv.z) + x3 * bf2f((unsigned short)asv.w);
    float pd = x0 * bf2f((unsigned short)adv.x) + x1 * bf2f((unsigned short)adv.y)
             + x2 * bf2f((unsigned short)adv.z) + x3 * bf2f((unsigned short)adv.w);
    for (int s = 1; s < 16; s <<= 1) { ps += __shfl_xor(ps, s); pd += __shfl_xor(pd, s); }
    if ((lane & 15) == 0) {
        int h = lane >> 4;
        s_src[(size_t)wid * 4 + h] = ps;
        s_dst[(size_t)wid * 4 + h] = pd;
    }
}

// ---------------- fused per-node softmax + aggregation (one wave per node) ----------------
__global__ __launch_bounds__(256) void attn_agg(
    const unsigned short* __restrict__ xw,
    const float* __restrict__ s_src, const float* __restrict__ s_dst,
    const int* __restrict__ off, const int* __restrict__ eidx,
    const int* __restrict__ rown, const unsigned short* __restrict__ bias,
    unsigned short* __restrict__ h_bf, float* __restrict__ h_f32,
    float* __restrict__ attn_acc, float* __restrict__ attn_out, int layer)
{
    int wid = (blockIdx.x * 256 + threadIdx.x) >> 6;
    int lane = threadIdx.x & 63;
    if (wid >= N_NODES) return;
    int n = wid;
    floatx4 sdv = *(const floatx4*)(s_dst + (size_t)n * 4);
    int base = off[n];
    int deg = off[n + 1] - base;

    // phase A: per-head max
    float m0 = -1e30f, m1 = -1e30f, m2 = -1e30f, m3 = -1e30f;
    for (int i = lane; i < deg; i += 64) {
        int e = eidx[base + i];
        int r = (e < N_EDGES) ? rown[e] : (e - N_EDGES);
        floatx4 sv = *(const floatx4*)(s_src + (size_t)r * 4);
        float t0 = sv.x + sdv.x; t0 = t0 > 0.f ? t0 : NEG_SLOPE * t0;
        float t1 = sv.y + sdv.y; t1 = t1 > 0.f ? t1 : NEG_SLOPE * t1;
        float t2 = sv.z + sdv.z; t2 = t2 > 0.f ? t2 : NEG_SLOPE * t2;
        float t3 = sv.w + sdv.w; t3 = t3 > 0.f ? t3 : NEG_SLOPE * t3;
        m0 = fmaxf(m0, t0); m1 = fmaxf(m1, t1); m2 = fmaxf(m2, t2); m3 = fmaxf(m3, t3);
    }
    for (int s = 1; s < 64; s <<= 1) {
        m0 = fmaxf(m0, __shfl_xor(m0, s)); m1 = fmaxf(m1, __shfl_xor(m1, s));
        m2 = fmaxf(m2, __shfl_xor(m2, s)); m3 = fmaxf(m3, __shfl_xor(m3, s));
    }

    // phase B: denominators
    float d0 = 0.f, d1 = 0.f, d2 = 0.f, d3 = 0.f;
    for (int i = lane; i < deg; i += 64) {
        int e = eidx[base + i];
        int r = (e < N_EDGES) ? rown[e] : (e - N_EDGES);
        floatx4 sv = *(const floatx4*)(s_src + (size_t)r * 4);
        float t0 = sv.x + sdv.x; t0 = t0 > 0.f ? t0 : NEG_SLOPE * t0;
        float t1 = sv.y + sdv.y; t1 = t1 > 0.f ? t1 : NEG_SLOPE * t1;
        float t2 = sv.z + sdv.z; t2 = t2 > 0.f ? t2 : NEG_SLOPE * t2;
        float t3 = sv.w + sdv.w; t3 = t3 > 0.f ? t3 : NEG_SLOPE * t3;
        d0 += __expf(t0 - m0); d1 += __expf(t1 - m1);
        d2 += __expf(t2 - m2); d3 += __expf(t3 - m3);
    }
    for (int s = 1; s < 64; s <<= 1) {
        d0 += __shfl_xor(d0, s); d1 += __shfl_xor(d1, s);
        d2 += __shfl_xor(d2, s); d3 += __shfl_xor(d3, s);
    }
    float i0 = 1.f / d0, i1 = 1.f / d1, i2 = 1.f / d2, i3 = 1.f / d3;

    // phase C: alpha + weighted feature gather
    int hl = lane >> 4;
    int f = lane * 4;
    float acc0 = 0.f, acc1 = 0.f, acc2 = 0.f, acc3 = 0.f;
    for (int c0 = 0; c0 < deg; c0 += 64) {
        int i = c0 + lane;
        int r = 0; float a0 = 0.f, a1 = 0.f, a2 = 0.f, a3 = 0.f;
        if (i < deg) {
            int e = eidx[base + i];
            r = (e < N_EDGES) ? rown[e] : (e - N_EDGES);
            floatx4 sv = *(const floatx4*)(s_src + (size_t)r * 4);
            float t0 = sv.x + sdv.x; t0 = t0 > 0.f ? t0 : NEG_SLOPE * t0;
            float t1 = sv.y + sdv.y; t1 = t1 > 0.f ? t1 : NEG_SLOPE * t1;
            float t2 = sv.z + sdv.z; t2 = t2 > 0.f ? t2 : NEG_SLOPE * t2;
            float t3 = sv.w + sdv.w; t3 = t3 > 0.f ? t3 : NEG_SLOPE * t3;
            a0 = __expf(t0 - m0) * i0; a1 = __expf(t1 - m1) * i1;
            a2 = __expf(t2 - m2) * i2; a3 = __expf(t3 - m3) * i3;
            float suma = 0.125f * (a0 + a1 + a2 + a3);
            if (layer == 0) attn_acc[e] = suma;
            else            attn_out[e] = attn_acc[e] + suma;
        }
        int cntc = deg - c0; if (cntc > 64) cntc = 64;
        for (int j = 0; j < cntc; j++) {
            int rj = __shfl(r, j);
            float b0 = __shfl(a0, j), b1 = __shfl(a1, j), b2 = __shfl(a2, j), b3 = __shfl(a3, j);
            float al = (hl == 0) ? b0 : ((hl == 1) ? b1 : ((hl == 2) ? b2 : b3));
            shortx4 xv = *(const shortx4*)(xw + (size_t)rj * DIM + f);
            acc0 += al * bf2f((unsigned short)xv.x);
            acc1 += al * bf2f((unsigned short)xv.y);
            acc2 += al * bf2f((unsigned short)xv.z);
            acc3 += al * bf2f((unsigned short)xv.w);
        }
    }
    shortx4 bv = *(const shortx4*)(bias + f);
    float o0 = acc0 + bf2f((unsigned short)bv.x);
    float o1 = acc1 + bf2f((unsigned short)bv.y);
    float o2 = acc2 + bf2f((unsigned short)bv.z);
    float o3 = acc3 + bf2f((unsigned short)bv.w);
    o0 = o0 > 0.f ? o0 : (__expf(o0) - 1.f);
    o1 = o1 > 0.f ? o1 : (__expf(o1) - 1.f);
    o2 = o2 > 0.f ? o2 : (__expf(o2) - 1.f);
    o3 = o3 > 0.f ? o3 : (__expf(o3) - 1.f);
    if (h_bf) {
        shortx4 pk;
        pk.x = (short)f2bf(o0); pk.y = (short)f2bf(o1);
        pk.z = (short)f2bf(o2); pk.w = (short)f2bf(o3);
        *(shortx4*)(h_bf + (size_t)n * DIM + f) = pk;
    }
    if (h_f32) {
        floatx4 pv; pv.x = o0; pv.y = o1; pv.z = o2; pv.w = o3;
        *(floatx4*)(h_f32 + (size_t)n * DIM + f) = pv;
    }
}

// ---------------- node predictor (wave per node, fp32 h) ----------------
__global__ __launch_bounds__(256) void node_pred(
    const float* __restrict__ h, const unsigned short* __restrict__ Wn,
    const unsigned short* __restrict__ bn, float* __restrict__ outp)
{
    int wid = (blockIdx.x * 256 + threadIdx.x) >> 6;
    int lane = threadIdx.x & 63;
    if (wid >= N_NODES) return;
    int f = lane * 4;
    floatx4 hv = *(const floatx4*)(h + (size_t)wid * DIM + f);
    shortx4 wv = *(const shortx4*)(Wn + f);
    float p = hv.x * bf2f((unsigned short)wv.x) + hv.y * bf2f((unsigned short)wv.y)
            + hv.z * bf2f((unsigned short)wv.z) + hv.w * bf2f((unsigned short)wv.w);
    for (int s = 1; s < 64; s <<= 1) p += __shfl_xor(p, s);
    if (lane == 0) outp[wid] = p + bf2f(bn[0]);
}

// ---------------- edge predictor (wave per edge, bf16 h and V) ----------------
__global__ __launch_bounds__(256) void edge_pred(
    const unsigned short* __restrict__ h, const unsigned short* __restrict__ V,
    const int* __restrict__ rown, const int* __restrict__ coln,
    const unsigned short* __restrict__ bb, float* __restrict__ outp, int o)
{
    int wid = (blockIdx.x * 256 + threadIdx.x) >> 6;
    int lane = threadIdx.x & 63;
    if (wid >= N_EDGES) return;
    int s = rown[wid], t = coln[wid];
    int f = lane * 4;
    shortx4 hv = *(const shortx4*)(h + (size_t)t * DIM + f);
    shortx4 vv = *(const shortx4*)(V + (size_t)s * DIM + f);
    float p = bf2f((unsigned short)hv.x) * bf2f((unsigned short)vv.x)
            + bf2f((unsigned short)hv.y) * bf2f((unsigned short)vv.y)
            + bf2f((unsigned short)hv.z) * bf2f((unsigned short)vv.z)
            + bf2f((unsigned short)hv.w) * bf2f((unsigned short)vv.w);
    for (int m = 1; m < 64; m <<= 1) p += __shfl_xor(p, m);
    if (lane == 0) outp[(size_t)wid * 3 + o] = p + bf2f(bb[o]);
}

extern "C" void kernel_launch(void* const* d_in, const int* in_sizes, int n_in,
                              void* d_out, int out_size, void* d_ws, size_t ws_size,
                              hipStream_t stream) {
    const void* x_raw  = d_in[0];
    const int*  ei_raw = (const int*)d_in[1];
    float* out = (float*)d_out;

    char* w = (char*)d_ws;
    size_t off_b = 0;
    auto alloc = [&](size_t bytes) -> char* {
        char* p = w + off_b; off_b = (off_b + bytes + 255) & ~(size_t)255; return p;
    };
    int*            flags  = (int*)alloc(256);
    unsigned short* buf0   = (unsigned short*)alloc((size_t)N_NODES * DIM * 2); // x_bf -> h(final) bf16
    unsigned short* buf1   = (unsigned short*)alloc((size_t)N_NODES * DIM * 2); // xw, later V
    unsigned short* buf2   = (unsigned short*)alloc((size_t)N_NODES * DIM * 2); // h1
    float*          ssrc   = (float*)alloc((size_t)N_NODES * 4 * 4);
    float*          sdst   = (float*)alloc((size_t)N_NODES * 4 * 4);
    float*          attn   = (float*)alloc((size_t)ETOT * 4);
    int*            cnt    = (int*)alloc((size_t)2 * N_NODES * 4);
    int*            cursor = cnt + N_NODES;
    int*            offs   = (int*)alloc((size_t)(N_NODES + 1) * 4);
    int*            eidx   = (int*)alloc((size_t)ETOT * 4);
    int*            rown   = (int*)alloc((size_t)N_EDGES * 4);
    int*            coln   = (int*)alloc((size_t)N_EDGES * 4);
    unsigned short* BT     = (unsigned short*)alloc((size_t)5 * 65536 * 2);
    unsigned short* small  = (unsigned short*)alloc(2048 * 2);
    // small: a1s@0 a1d@256 b1@512 a2s@768 a2d@1024 b2@1280 Wn@1536 bn@1792 bb@1793

    float* out_node = out;              // [50000]
    float* out_edge = out + 50000;      // [800000,3]
    float* out_h    = out + 2450000;    // [50000,256]
    float* out_attn = out + 15250000;   // [850000]

    int eb = (ETOT + 255) / 256;
    int node_wave_blocks = (N_NODES * 64) / 256;
    int edge_wave_blocks = (N_EDGES * 64) / 256;
    dim3 gg((N_NODES + 127) / 128, 2);

    detect_kernel<<<1, 256, 0, stream>>>((const unsigned short*)x_raw, ei_raw, flags);
    norm_x<<<12500, 256, 0, stream>>>(x_raw, buf0, flags);
    norm_small<<<1, 256, 0, stream>>>(d_in[3],  small + 0,    256, flags);
    norm_small<<<1, 256, 0, stream>>>(d_in[4],  small + 256,  256, flags);
    norm_small<<<1, 256, 0, stream>>>(d_in[5],  small + 512,  256, flags);
    norm_small<<<1, 256, 0, stream>>>(d_in[7],  small + 768,  256, flags);
    norm_small<<<1, 256, 0, stream>>>(d_in[8],  small + 1024, 256, flags);
    norm_small<<<1, 256, 0, stream>>>(d_in[9],  small + 1280, 256, flags);
    norm_small<<<1, 256, 0, stream>>>(d_in[10], small + 1536, 256, flags);
    norm_small<<<1, 256, 0, stream>>>(d_in[11], small + 1792, 1,   flags);
    norm_small<<<1, 256, 0, stream>>>(d_in[13], small + 1793, 3,   flags);
    norm_edges<<<3125, 256, 0, stream>>>(ei_raw, rown, coln, flags);
    transpose_kernel<<<1280, 256, 0, stream>>>(d_in[2], d_in[6], d_in[12], BT, flags);

    zero_kernel<<<(2 * N_NODES + 255) / 256, 256, 0, stream>>>(cnt, 2 * N_NODES);
    count_kernel<<<eb, 256, 0, stream>>>(coln, cnt);
    scan_kernel<<<1, 1024, 0, stream>>>(cnt, offs);
    fill_kernel<<<eb, 256, 0, stream>>>(coln, offs, cursor, eidx);

    // ---- layer 1: x(buf0) -> xw(buf1); h1 -> buf2 (bf16) ----
    gemm256<<<gg, 256, 0, stream>>>(buf0, BT, buf1, N_NODES);
    s_kernel<<<node_wave_blocks, 256, 0, stream>>>(buf1, small + 0, small + 256, ssrc, sdst);
    attn_agg<<<node_wave_blocks, 256, 0, stream>>>(buf1, ssrc, sdst, offs, eidx, rown,
                                                   small + 512, buf2, nullptr, attn, nullptr, 0);

    // ---- layer 2: h1(buf2) -> xw(buf1); h -> buf0 (bf16) + out_h (fp32) ----
    gemm256<<<gg, 256, 0, stream>>>(buf2, BT + 65536, buf1, N_NODES);
    s_kernel<<<node_wave_blocks, 256, 0, stream>>>(buf1, small + 768, small + 1024, ssrc, sdst);
    attn_agg<<<node_wave_blocks, 256, 0, stream>>>(buf1, ssrc, sdst, offs, eidx, rown,
                                                   small + 1280, buf0, out_h, attn, out_attn, 1);

    // ---- heads: V_o = h @ Wb[o] -> buf1 (bf16); edge dots in bf16 ----
    for (int o = 0; o < 3; o++) {
        gemm256<<<gg, 256, 0, stream>>>(buf0, BT + (size_t)(2 + o) * 65536, buf1, N_NODES);
        edge_pred<<<edge_wave_blocks, 256, 0, stream>>>(buf0, buf1, rown, coln,
                                                        small + 1793, out_edge, o);
    }
    node_pred<<<node_wave_blocks, 256, 0, stream>>>(out_h, small + 1536, small + 1792, out_node);
}

// Round 8
// 882.052 us; speedup vs baseline: 4.3432x; 1.3149x over previous
//
#include <hip/hip_runtime.h>
#include <hip/hip_bf16.h>

#define N_NODES 50000
#define N_EDGES 800000
#define ETOT    (N_EDGES + N_NODES)
#define DIM     256
#define NEG_SLOPE 0.2f

typedef __attribute__((ext_vector_type(4))) float  floatx4;
typedef __attribute__((ext_vector_type(8))) short  shortx8;
typedef __attribute__((ext_vector_type(4))) short  shortx4;

__device__ inline float bf2f(unsigned short u) {
    union { unsigned int i; float f; } c; c.i = ((unsigned int)u) << 16; return c.f;
}
__device__ inline unsigned short f2bf(float x) {
    union { float f; unsigned int i; } c; c.f = x;
    unsigned int r = c.i + 0x7FFF + ((c.i >> 16) & 1);
    return (unsigned short)(r >> 16);
}

// ---------------- dtype detection ----------------
__global__ void detect_kernel(const unsigned short* __restrict__ xs,
                              const int* __restrict__ ei, int* __restrict__ flags) {
    int tid = threadIdx.x;
    unsigned short s = xs[2 * tid];
    float av = fabsf(bf2f(s));
    int hit = (av > 0.001f && av < 100.0f) ? 1 : 0;
    int odd = ei[2 * tid + 1];
    __shared__ int sh_hit[256], sh_nz[256];
    sh_hit[tid] = hit; sh_nz[tid] = (odd != 0) ? 1 : 0;
    __syncthreads();
    for (int st = 128; st > 0; st >>= 1) {
        if (tid < st) { sh_hit[tid] += sh_hit[tid + st]; sh_nz[tid] += sh_nz[tid + st]; }
        __syncthreads();
    }
    if (tid == 0) {
        flags[0] = (sh_hit[0] < 128) ? 1 : 0;   // 1 = fp32 floats
        flags[1] = (sh_nz[0] == 0) ? 1 : 0;     // 1 = int64 edge_index
    }
}

// ---------------- input normalization ----------------
__global__ void norm_x(const void* __restrict__ src, unsigned short* __restrict__ dst,
                       const int* __restrict__ flags) {
    int i = (blockIdx.x * 256 + threadIdx.x) * 4;
    if (flags[0]) {
        const float* s = (const float*)src;
        dst[i + 0] = f2bf(s[i + 0]); dst[i + 1] = f2bf(s[i + 1]);
        dst[i + 2] = f2bf(s[i + 2]); dst[i + 3] = f2bf(s[i + 3]);
    } else {
        *(shortx4*)(dst + i) = *(const shortx4*)((const unsigned short*)src + i);
    }
}

__global__ void norm_small(const void* __restrict__ src, unsigned short* __restrict__ dst,
                           int count, const int* __restrict__ flags) {
    int i = blockIdx.x * 256 + threadIdx.x;
    if (i >= count) return;
    dst[i] = flags[0] ? f2bf(((const float*)src)[i]) : ((const unsigned short*)src)[i];
}

__global__ void norm_edges(const int* __restrict__ ei, int* __restrict__ rown,
                           int* __restrict__ coln, const int* __restrict__ flags) {
    int e = blockIdx.x * 256 + threadIdx.x;
    if (e >= N_EDGES) return;
    if (flags[1]) { rown[e] = ei[2 * e]; coln[e] = ei[2 * (N_EDGES + e)]; }
    else          { rown[e] = ei[e];     coln[e] = ei[N_EDGES + e]; }
}

// ---------------- weight transpose (5 x [256,256] -> B^T bf16) ----------------
__global__ void transpose_kernel(const void* __restrict__ W1, const void* __restrict__ W2,
                                 const void* __restrict__ Wb, unsigned short* __restrict__ BT,
                                 const int* __restrict__ flags) {
    int idx = blockIdx.x * 256 + threadIdx.x;   // < 5*65536
    int m = idx >> 16, rem = idx & 65535;
    int k = rem >> 8, nn = rem & 255;
    const void* src = (m == 0) ? W1 : ((m == 1) ? W2 : Wb);
    size_t el = (m >= 2) ? ((size_t)(m - 2) * 65536 + rem) : (size_t)rem;
    unsigned short val = flags[0] ? f2bf(((const float*)src)[el])
                                  : ((const unsigned short*)src)[el];
    BT[(size_t)m * 65536 + nn * 256 + k] = val;
}

// ---------------- CSR build ----------------
__global__ void zero_kernel(int* p, int n) {
    int i = blockIdx.x * 256 + threadIdx.x;
    if (i < n) p[i] = 0;
}

__global__ void count_kernel(const int* __restrict__ coln, int* __restrict__ cnt) {
    int e = blockIdx.x * 256 + threadIdx.x;
    if (e >= ETOT) return;
    int c = (e < N_EDGES) ? coln[e] : (e - N_EDGES);
    atomicAdd(&cnt[c], 1);
}

__global__ void scan_kernel(const int* __restrict__ cnt, int* __restrict__ off) {
    __shared__ int buf[1024];
    __shared__ int carry;
    if (threadIdx.x == 0) carry = 0;
    __syncthreads();
    for (int base = 0; base < N_NODES; base += 1024) {
        int i = base + threadIdx.x;
        int v = (i < N_NODES) ? cnt[i] : 0;
        buf[threadIdx.x] = v;
        __syncthreads();
        for (int s = 1; s < 1024; s <<= 1) {
            int t = (threadIdx.x >= s) ? buf[threadIdx.x - s] : 0;
            __syncthreads();
            buf[threadIdx.x] += t;
            __syncthreads();
        }
        int incl = buf[threadIdx.x];
        int total = buf[1023];
        if (i < N_NODES) off[i] = carry + incl - v;
        __syncthreads();
        if (threadIdx.x == 0) carry += total;
        __syncthreads();
    }
    if (threadIdx.x == 0) off[N_NODES] = carry;
}

__global__ void fill_kernel(const int* __restrict__ coln, const int* __restrict__ off,
                            int* __restrict__ cursor, int* __restrict__ eidx) {
    int e = blockIdx.x * 256 + threadIdx.x;
    if (e >= ETOT) return;
    int c = (e < N_EDGES) ? coln[e] : (e - N_EDGES);
    int p = atomicAdd(&cursor[c], 1);
    eidx[off[c] + p] = e;
}

// ---------------- bf16 MFMA GEMM: C[M,Nc] = A[M,256] * B (BT given, Nc cols) ----------------
__global__ __launch_bounds__(256) void gemm256(
    const unsigned short* __restrict__ A,
    const unsigned short* __restrict__ BT,   // [Nc,256] rows = B columns
    unsigned short* __restrict__ Cb, int M, int Nc)
{
    __shared__ short As[128 * 32];
    __shared__ short Bs[128 * 32];
    int tid = threadIdx.x, lane = tid & 63, wave = tid >> 6;
    int wm = wave & 1, wn = wave >> 1;
    int m0 = blockIdx.x * 128, n0 = blockIdx.y * 128;
    floatx4 acc[4][4] = {};
    for (int k0 = 0; k0 < 256; k0 += 32) {
        __syncthreads();
#pragma unroll
        for (int i = 0; i < 2; i++) {
            int c = i * 256 + tid;
            int row = c >> 2, koff = (c & 3) * 8;
            int gr = m0 + row; if (gr > M - 1) gr = M - 1;
            shortx8 av = *(const shortx8*)(A + (size_t)gr * 256 + k0 + koff);
            *(shortx8*)(As + row * 32 + koff) = av;
            int gn = n0 + row;
            shortx8 bv = *(const shortx8*)(BT + (size_t)gn * 256 + k0 + koff);
            *(shortx8*)(Bs + row * 32 + koff) = bv;
        }
        __syncthreads();
        shortx8 af[4], bfr[4];
#pragma unroll
        for (int mt = 0; mt < 4; mt++)
            af[mt] = *(const shortx8*)(As + (wm * 64 + mt * 16 + (lane & 15)) * 32 + (lane >> 4) * 8);
#pragma unroll
        for (int nt = 0; nt < 4; nt++)
            bfr[nt] = *(const shortx8*)(Bs + (wn * 64 + nt * 16 + (lane & 15)) * 32 + (lane >> 4) * 8);
#pragma unroll
        for (int mt = 0; mt < 4; mt++)
#pragma unroll
            for (int nt = 0; nt < 4; nt++)
                acc[mt][nt] = __builtin_amdgcn_mfma_f32_16x16x32_bf16(af[mt], bfr[nt], acc[mt][nt], 0, 0, 0);
    }
#pragma unroll
    for (int mt = 0; mt < 4; mt++) {
#pragma unroll
        for (int r = 0; r < 4; r++) {
            int grow = m0 + wm * 64 + mt * 16 + (lane >> 4) * 4 + r;
            if (grow >= M) continue;
#pragma unroll
            for (int nt = 0; nt < 4; nt++) {
                int gcol = n0 + wn * 64 + nt * 16 + (lane & 15);
                Cb[(size_t)grow * Nc + gcol] = f2bf(acc[mt][nt][r]);
            }
        }
    }
}

// ---------------- attention scores (wave per node) ----------------
__global__ __launch_bounds__(256) void s_kernel(
    const unsigned short* __restrict__ xw,
    const unsigned short* __restrict__ a_src,
    const unsigned short* __restrict__ a_dst,
    float* __restrict__ s_src, float* __restrict__ s_dst)
{
    int wid = (blockIdx.x * 256 + threadIdx.x) >> 6;
    int lane = threadIdx.x & 63;
    if (wid >= N_NODES) return;
    int f = lane * 4;
    shortx4 xv = *(const shortx4*)(xw + (size_t)wid * DIM + f);
    shortx4 asv = *(const shortx4*)(a_src + f);
    shortx4 adv = *(const shortx4*)(a_dst + f);
    float x0 = bf2f((unsigned short)xv.x), x1 = bf2f((unsigned short)xv.y);
    float x2 = bf2f((unsigned short)xv.z), x3 = bf2f((unsigned short)xv.w);
    float ps = x0 * bf2f((unsigned short)asv.x) + x1 * bf2f((unsigned short)asv.y)
             + x2 * bf2f((unsigned short)asv.z) + x3 * bf2f((unsigned short)asv.w);
    float pd = x0 * bf2f((unsigned short)adv.x) + x1 * bf2f((unsigned short)adv.y)
             + x2 * bf2f((unsigned short)adv.z) + x3 * bf2f((unsigned short)adv.w);
    for (int s = 1; s < 16; s <<= 1) { ps += __shfl_xor(ps, s); pd += __shfl_xor(pd, s); }
    if ((lane & 15) == 0) {
        int h = lane >> 4;
        s_src[(size_t)wid * 4 + h] = ps;
        s_dst[(size_t)wid * 4 + h] = pd;
    }
}

// ---------------- fused per-node online-softmax + aggregation (one wave per node) ----------------
__global__ __launch_bounds__(256) void attn_agg(
    const unsigned short* __restrict__ xw,
    const float* __restrict__ s_src, const float* __restrict__ s_dst,
    const int* __restrict__ off, const int* __restrict__ eidx,
    const int* __restrict__ rown, const unsigned short* __restrict__ bias,
    unsigned short* __restrict__ h_bf, float* __restrict__ h_f32,
    float* __restrict__ attn_acc, float* __restrict__ attn_out, int layer)
{
    int wid = (blockIdx.x * 256 + threadIdx.x) >> 6;
    int lane = threadIdx.x & 63;
    if (wid >= N_NODES) return;
    int n = wid;
    floatx4 sdv = *(const floatx4*)(s_dst + (size_t)n * 4);
    int base = off[n];
    int deg = off[n + 1] - base;

    // phase A+B fused: online (max, denom)
    float m0 = -1e30f, m1 = -1e30f, m2 = -1e30f, m3 = -1e30f;
    float d0 = 0.f, d1 = 0.f, d2 = 0.f, d3 = 0.f;
    for (int i = lane; i < deg; i += 64) {
        int e = eidx[base + i];
        int r = (e < N_EDGES) ? rown[e] : (e - N_EDGES);
        floatx4 sv = *(const floatx4*)(s_src + (size_t)r * 4);
        float t0 = sv.x + sdv.x; t0 = t0 > 0.f ? t0 : NEG_SLOPE * t0;
        float t1 = sv.y + sdv.y; t1 = t1 > 0.f ? t1 : NEG_SLOPE * t1;
        float t2 = sv.z + sdv.z; t2 = t2 > 0.f ? t2 : NEG_SLOPE * t2;
        float t3 = sv.w + sdv.w; t3 = t3 > 0.f ? t3 : NEG_SLOPE * t3;
        float nm;
        nm = fmaxf(m0, t0); d0 = d0 * __expf(m0 - nm) + __expf(t0 - nm); m0 = nm;
        nm = fmaxf(m1, t1); d1 = d1 * __expf(m1 - nm) + __expf(t1 - nm); m1 = nm;
        nm = fmaxf(m2, t2); d2 = d2 * __expf(m2 - nm) + __expf(t2 - nm); m2 = nm;
        nm = fmaxf(m3, t3); d3 = d3 * __expf(m3 - nm) + __expf(t3 - nm); m3 = nm;
    }
    for (int s = 1; s < 64; s <<= 1) {
        float om, od, nm;
        om = __shfl_xor(m0, s); od = __shfl_xor(d0, s);
        nm = fmaxf(m0, om); d0 = d0 * __expf(m0 - nm) + od * __expf(om - nm); m0 = nm;
        om = __shfl_xor(m1, s); od = __shfl_xor(d1, s);
        nm = fmaxf(m1, om); d1 = d1 * __expf(m1 - nm) + od * __expf(om - nm); m1 = nm;
        om = __shfl_xor(m2, s); od = __shfl_xor(d2, s);
        nm = fmaxf(m2, om); d2 = d2 * __expf(m2 - nm) + od * __expf(om - nm); m2 = nm;
        om = __shfl_xor(m3, s); od = __shfl_xor(d3, s);
        nm = fmaxf(m3, om); d3 = d3 * __expf(m3 - nm) + od * __expf(om - nm); m3 = nm;
    }
    float i0 = 1.f / d0, i1 = 1.f / d1, i2 = 1.f / d2, i3 = 1.f / d3;

    // phase C: alpha + weighted feature gather
    int hl = lane >> 4;
    int f = lane * 4;
    float acc0 = 0.f, acc1 = 0.f, acc2 = 0.f, acc3 = 0.f;
    for (int c0 = 0; c0 < deg; c0 += 64) {
        int i = c0 + lane;
        int r = 0; float a0 = 0.f, a1 = 0.f, a2 = 0.f, a3 = 0.f;
        if (i < deg) {
            int e = eidx[base + i];
            r = (e < N_EDGES) ? rown[e] : (e - N_EDGES);
            floatx4 sv = *(const floatx4*)(s_src + (size_t)r * 4);
            float t0 = sv.x + sdv.x; t0 = t0 > 0.f ? t0 : NEG_SLOPE * t0;
            float t1 = sv.y + sdv.y; t1 = t1 > 0.f ? t1 : NEG_SLOPE * t1;
            float t2 = sv.z + sdv.z; t2 = t2 > 0.f ? t2 : NEG_SLOPE * t2;
            float t3 = sv.w + sdv.w; t3 = t3 > 0.f ? t3 : NEG_SLOPE * t3;
            a0 = __expf(t0 - m0) * i0; a1 = __expf(t1 - m1) * i1;
            a2 = __expf(t2 - m2) * i2; a3 = __expf(t3 - m3) * i3;
            float suma = 0.125f * (a0 + a1 + a2 + a3);
            if (layer == 0) attn_acc[e] = suma;
            else            attn_out[e] = attn_acc[e] + suma;
        }
        int cntc = deg - c0; if (cntc > 64) cntc = 64;
        for (int j = 0; j < cntc; j++) {
            int rj = __shfl(r, j);
            float b0 = __shfl(a0, j), b1 = __shfl(a1, j), b2 = __shfl(a2, j), b3 = __shfl(a3, j);
            float al = (hl == 0) ? b0 : ((hl == 1) ? b1 : ((hl == 2) ? b2 : b3));
            shortx4 xv = *(const shortx4*)(xw + (size_t)rj * DIM + f);
            acc0 += al * bf2f((unsigned short)xv.x);
            acc1 += al * bf2f((unsigned short)xv.y);
            acc2 += al * bf2f((unsigned short)xv.z);
            acc3 += al * bf2f((unsigned short)xv.w);
        }
    }
    shortx4 bv = *(const shortx4*)(bias + f);
    float o0 = acc0 + bf2f((unsigned short)bv.x);
    float o1 = acc1 + bf2f((unsigned short)bv.y);
    float o2 = acc2 + bf2f((unsigned short)bv.z);
    float o3 = acc3 + bf2f((unsigned short)bv.w);
    o0 = o0 > 0.f ? o0 : (__expf(o0) - 1.f);
    o1 = o1 > 0.f ? o1 : (__expf(o1) - 1.f);
    o2 = o2 > 0.f ? o2 : (__expf(o2) - 1.f);
    o3 = o3 > 0.f ? o3 : (__expf(o3) - 1.f);
    if (h_bf) {
        shortx4 pk;
        pk.x = (short)f2bf(o0); pk.y = (short)f2bf(o1);
        pk.z = (short)f2bf(o2); pk.w = (short)f2bf(o3);
        *(shortx4*)(h_bf + (size_t)n * DIM + f) = pk;
    }
    if (h_f32) {
        floatx4 pv; pv.x = o0; pv.y = o1; pv.z = o2; pv.w = o3;
        *(floatx4*)(h_f32 + (size_t)n * DIM + f) = pv;
    }
}

// ---------------- node predictor (wave per node, bf16 h) ----------------
__global__ __launch_bounds__(256) void node_pred(
    const unsigned short* __restrict__ h, const unsigned short* __restrict__ Wn,
    const unsigned short* __restrict__ bn, float* __restrict__ outp)
{
    int wid = (blockIdx.x * 256 + threadIdx.x) >> 6;
    int lane = threadIdx.x & 63;
    if (wid >= N_NODES) return;
    int f = lane * 4;
    shortx4 hv = *(const shortx4*)(h + (size_t)wid * DIM + f);
    shortx4 wv = *(const shortx4*)(Wn + f);
    float p = bf2f((unsigned short)hv.x) * bf2f((unsigned short)wv.x)
            + bf2f((unsigned short)hv.y) * bf2f((unsigned short)wv.y)
            + bf2f((unsigned short)hv.z) * bf2f((unsigned short)wv.z)
            + bf2f((unsigned short)hv.w) * bf2f((unsigned short)wv.w);
    for (int s = 1; s < 64; s <<= 1) p += __shfl_xor(p, s);
    if (lane == 0) outp[wid] = p + bf2f(bn[0]);
}

// ---------------- fused edge predictor: one wave per edge, 3 outputs ----------------
__global__ __launch_bounds__(256) void edge_pred_fused(
    const unsigned short* __restrict__ h,   // bf16 [N,256]
    const unsigned short* __restrict__ V,   // bf16 [N,768] interleaved V0|V1|V2
    const int* __restrict__ rown, const int* __restrict__ coln,
    const unsigned short* __restrict__ bb, float* __restrict__ outp)
{
    int wid = (blockIdx.x * 256 + threadIdx.x) >> 6;
    int lane = threadIdx.x & 63;
    if (wid >= N_EDGES) return;
    int s = rown[wid], t = coln[wid];
    int f = lane * 4;
    shortx4 hv = *(const shortx4*)(h + (size_t)t * DIM + f);
    float h0 = bf2f((unsigned short)hv.x), h1 = bf2f((unsigned short)hv.y);
    float h2 = bf2f((unsigned short)hv.z), h3 = bf2f((unsigned short)hv.w);
    const unsigned short* vrow = V + (size_t)s * 768;
    float p[3];
#pragma unroll
    for (int o = 0; o < 3; o++) {
        shortx4 vv = *(const shortx4*)(vrow + o * 256 + f);
        p[o] = h0 * bf2f((unsigned short)vv.x) + h1 * bf2f((unsigned short)vv.y)
             + h2 * bf2f((unsigned short)vv.z) + h3 * bf2f((unsigned short)vv.w);
    }
    for (int m = 1; m < 64; m <<= 1) {
        p[0] += __shfl_xor(p[0], m);
        p[1] += __shfl_xor(p[1], m);
        p[2] += __shfl_xor(p[2], m);
    }
    if (lane == 0) {
        outp[(size_t)wid * 3 + 0] = p[0] + bf2f(bb[0]);
        outp[(size_t)wid * 3 + 1] = p[1] + bf2f(bb[1]);
        outp[(size_t)wid * 3 + 2] = p[2] + bf2f(bb[2]);
    }
}

extern "C" void kernel_launch(void* const* d_in, const int* in_sizes, int n_in,
                              void* d_out, int out_size, void* d_ws, size_t ws_size,
                              hipStream_t stream) {
    const void* x_raw  = d_in[0];
    const int*  ei_raw = (const int*)d_in[1];
    float* out = (float*)d_out;

    char* w = (char*)d_ws;
    size_t off_b = 0;
    auto alloc = [&](size_t bytes) -> char* {
        char* p = w + off_b; off_b = (off_b + bytes + 255) & ~(size_t)255; return p;
    };
    int*            flags  = (int*)alloc(256);
    unsigned short* buf0   = (unsigned short*)alloc((size_t)N_NODES * DIM * 2); // x_bf -> h(final) bf16
    // region R: buf1 (xw) and buf2 (h1) early; V [N,768] later (aliases both)
    unsigned short* R      = (unsigned short*)alloc((size_t)N_NODES * 768 * 2); // 76.8 MB
    unsigned short* buf1   = R;                       // xw
    unsigned short* buf2   = R + (size_t)N_NODES * DIM; // h1
    unsigned short* V      = R;                       // [N,768] after layer 2
    float*          ssrc   = (float*)alloc((size_t)N_NODES * 4 * 4);
    float*          sdst   = (float*)alloc((size_t)N_NODES * 4 * 4);
    float*          attn   = (float*)alloc((size_t)ETOT * 4);
    int*            cnt    = (int*)alloc((size_t)2 * N_NODES * 4);
    int*            cursor = cnt + N_NODES;
    int*            offs   = (int*)alloc((size_t)(N_NODES + 1) * 4);
    int*            eidx   = (int*)alloc((size_t)ETOT * 4);
    int*            rown   = (int*)alloc((size_t)N_EDGES * 4);
    int*            coln   = (int*)alloc((size_t)N_EDGES * 4);
    unsigned short* BT     = (unsigned short*)alloc((size_t)5 * 65536 * 2);
    unsigned short* small  = (unsigned short*)alloc(2048 * 2);
    // small: a1s@0 a1d@256 b1@512 a2s@768 a2d@1024 b2@1280 Wn@1536 bn@1792 bb@1793

    float* out_node = out;              // [50000]
    float* out_edge = out + 50000;      // [800000,3]
    float* out_h    = out + 2450000;    // [50000,256]
    float* out_attn = out + 15250000;   // [850000]

    int eb = (ETOT + 255) / 256;
    int node_wave_blocks = (N_NODES * 64) / 256;
    int edge_wave_blocks = (N_EDGES * 64) / 256;
    dim3 gg((N_NODES + 127) / 128, 2);
    dim3 gv((N_NODES + 127) / 128, 6);

    detect_kernel<<<1, 256, 0, stream>>>((const unsigned short*)x_raw, ei_raw, flags);
    norm_x<<<12500, 256, 0, stream>>>(x_raw, buf0, flags);
    norm_small<<<1, 256, 0, stream>>>(d_in[3],  small + 0,    256, flags);
    norm_small<<<1, 256, 0, stream>>>(d_in[4],  small + 256,  256, flags);
    norm_small<<<1, 256, 0, stream>>>(d_in[5],  small + 512,  256, flags);
    norm_small<<<1, 256, 0, stream>>>(d_in[7],  small + 768,  256, flags);
    norm_small<<<1, 256, 0, stream>>>(d_in[8],  small + 1024, 256, flags);
    norm_small<<<1, 256, 0, stream>>>(d_in[9],  small + 1280, 256, flags);
    norm_small<<<1, 256, 0, stream>>>(d_in[10], small + 1536, 256, flags);
    norm_small<<<1, 256, 0, stream>>>(d_in[11], small + 1792, 1,   flags);
    norm_small<<<1, 256, 0, stream>>>(d_in[13], small + 1793, 3,   flags);
    norm_edges<<<3125, 256, 0, stream>>>(ei_raw, rown, coln, flags);
    transpose_kernel<<<1280, 256, 0, stream>>>(d_in[2], d_in[6], d_in[12], BT, flags);

    zero_kernel<<<(2 * N_NODES + 255) / 256, 256, 0, stream>>>(cnt, 2 * N_NODES);
    count_kernel<<<eb, 256, 0, stream>>>(coln, cnt);
    scan_kernel<<<1, 1024, 0, stream>>>(cnt, offs);
    fill_kernel<<<eb, 256, 0, stream>>>(coln, offs, cursor, eidx);

    // ---- layer 1: x(buf0) -> xw(buf1); h1 -> buf2 ----
    gemm256<<<gg, 256, 0, stream>>>(buf0, BT, buf1, N_NODES, 256);
    s_kernel<<<node_wave_blocks, 256, 0, stream>>>(buf1, small + 0, small + 256, ssrc, sdst);
    attn_agg<<<node_wave_blocks, 256, 0, stream>>>(buf1, ssrc, sdst, offs, eidx, rown,
                                                   small + 512, buf2, nullptr, attn, nullptr, 0);

    // ---- layer 2: h1(buf2) -> xw(buf1); h -> buf0 (bf16) + out_h (fp32) ----
    gemm256<<<gg, 256, 0, stream>>>(buf2, BT + 65536, buf1, N_NODES, 256);
    s_kernel<<<node_wave_blocks, 256, 0, stream>>>(buf1, small + 768, small + 1024, ssrc, sdst);
    attn_agg<<<node_wave_blocks, 256, 0, stream>>>(buf1, ssrc, sdst, offs, eidx, rown,
                                                   small + 1280, buf0, out_h, attn, out_attn, 1);

    // ---- edge head: V[N,768] = h @ [Wb0|Wb1|Wb2] in ONE gemm; fused edge dots ----
    gemm256<<<gv, 256, 0, stream>>>(buf0, BT + 2 * 65536, V, N_NODES, 768);
    edge_pred_fused<<<edge_wave_blocks, 256, 0, stream>>>(buf0, V, rown, coln,
                                                          small + 1793, out_edge);
    node_pred<<<node_wave_blocks, 256, 0, stream>>>(buf0, small + 1536, small + 1792, out_node);
}